// Round 5
// baseline (342.595 us; speedup 1.0000x reference)
//
#include <hip/hip_runtime.h>
#include <hip/hip_bf16.h>

using uint32 = unsigned int;
using u16 = unsigned short;
using short8 = __attribute__((ext_vector_type(8))) short;
using f32x4  = __attribute__((ext_vector_type(4))) float;

// ---------- bf16 helpers ----------
__device__ __forceinline__ float bf2f(u16 u) {
  union { uint32 i; float f; } c; c.i = ((uint32)u) << 16; return c.f;
}
__device__ __forceinline__ u16 f2bf(float f) {
  union { float f; uint32 i; } c; c.f = f;
  uint32 u = c.i;
  u += 0x7fffu + ((u >> 16) & 1u);   // RNE
  return (u16)(u >> 16);
}
__device__ __forceinline__ uint32 pack2(float a, float b) {
  return (uint32)f2bf(a) | ((uint32)f2bf(b) << 16);
}

// Sizes: B=16, C=64, W=256, H=128, H'=122, KW=7
// k/q layout: [b][co][w][h'] contiguous == (B,256,7808) attention rows
// v = x raw: (B,256,8192); z = x + P*V in same raw layout (== NCHW image)

// ---------------------------------------------------------------
// Kernel 0: prep weights -> bf16 [kw][co][ci]
// ---------------------------------------------------------------
__global__ __launch_bounds__(256) void prep_weights(
    const float* __restrict__ wK, const float* __restrict__ wQ,
    const float* __restrict__ wV,
    u16* __restrict__ pK, u16* __restrict__ pQ, u16* __restrict__ pV)
{
  int idx = blockIdx.x * 256 + threadIdx.x;   // 0..86015
  if (idx >= 86016) return;
  int set = idx / 28672;
  int r = idx - set * 28672;                  // kw*4096 + co*64 + ci
  int kw = r >> 12;
  int rem = r & 4095;
  int co = rem >> 6, ci = rem & 63;
  const float* src = set == 0 ? wK : (set == 1 ? wQ : wV);
  u16* dst = set == 0 ? pK : (set == 1 ? pQ : pV);
  dst[r] = f2bf(src[co * 448 + ci * 7 + kw]);
}

// ---------------------------------------------------------------
// Kernel 1: K and Q convs via MFMA. Block = one (b,w), 4 waves.
// wave = co-tile (16 co); A-frags (weights) DIRECT FROM GLOBAL (L2-resident,
// each frag read once per block); B-frags (x) from swizzled LDS tile.
// ONE barrier per block; no weight staging.
// ---------------------------------------------------------------
__global__ __launch_bounds__(256) void conv_kq_mfma(
    const float* __restrict__ x,
    const u16* __restrict__ wpK, const u16* __restrict__ wpQ,
    const float* __restrict__ bK, const float* __restrict__ bQ,
    u16* __restrict__ qbuf, u16* __restrict__ kbuf)
{
  __shared__ u16 xt[136 * 64];
  const int bid = blockIdx.x;
  const int b = bid >> 8, w = bid & 255;
  const int t = threadIdx.x;
  const int lane = t & 63, wv = t >> 6;
  const int ln = lane & 15, g = lane >> 4;

  // stage x -> xt[h][ci ^ ((h&7)<<3)], bf16, transposed
  {
    const float* xb = x + (size_t)b * 2097152 + (size_t)w * 128;
    #pragma unroll
    for (int it = 0; it < 8; ++it) {
      int idx = t + it * 256;
      int h = idx & 127, gq = idx >> 7;    // gq 0..15 -> ci quad
      int ci0 = gq * 4;
      float v0 = xb[(size_t)(ci0 + 0) * 32768 + h];
      float v1 = xb[(size_t)(ci0 + 1) * 32768 + h];
      float v2 = xb[(size_t)(ci0 + 2) * 32768 + h];
      float v3 = xb[(size_t)(ci0 + 3) * 32768 + h];
      uint2 pk;
      pk.x = pack2(v0, v1);
      pk.y = pack2(v2, v3);
      int col = ci0 ^ ((h & 7) << 3);
      *reinterpret_cast<uint2*>(&xt[h * 64 + col]) = pk;
    }
    if (t < 128) {   // zero pad rows 128..135
      int h = 128 + (t >> 4), gq = t & 15;
      *reinterpret_cast<uint2*>(&xt[h * 64 + gq * 4]) = make_uint2(0u, 0u);
    }
  }
  __syncthreads();

  f32x4 accK[8], accQ[8];
  #pragma unroll
  for (int j = 0; j < 8; ++j) { accK[j] = (f32x4)0.f; accQ[j] = (f32x4)0.f; }

  for (int kw = 0; kw < 7; ++kw) {
    #pragma unroll
    for (int ks = 0; ks < 2; ++ks) {
      const int kb = ks * 32 + g * 8;
      // A-frag: lane -> weight row (co = wv*16+ln), k-slice kb (16B aligned)
      const size_t woff = (size_t)(kw * 64 + wv * 16 + ln) * 64 + kb;
      short8 aK = *reinterpret_cast<const short8*>(wpK + woff);
      short8 aQ = *reinterpret_cast<const short8*>(wpQ + woff);
      #pragma unroll
      for (int j = 0; j < 8; ++j) {
        int row = j * 16 + ln + kw;
        int col = kb ^ ((row & 7) << 3);
        short8 bf = *reinterpret_cast<const short8*>(&xt[row * 64 + col]);
        accK[j] = __builtin_amdgcn_mfma_f32_16x16x32_bf16(aK, bf, accK[j], 0, 0, 0);
        accQ[j] = __builtin_amdgcn_mfma_f32_16x16x32_bf16(aQ, bf, accQ[j], 0, 0, 0);
      }
    }
  }

  // D: col = ln -> n, row = g*4 + r -> co within wave tile
  #pragma unroll
  for (int r = 0; r < 4; ++r) {
    int co = wv * 16 + g * 4 + r;
    float bk = bK[co], bq = bQ[co];
    size_t base = ((size_t)(b * 64 + co) * 256 + w) * 122;
    #pragma unroll
    for (int j = 0; j < 8; ++j) {
      int n = j * 16 + ln;
      if (n < 122) {
        kbuf[base + n] = f2bf(accK[j][r] + bk);
        qbuf[base + n] = f2bf(accQ[j][r] + bq);
      }
    }
  }
}

// ---------------------------------------------------------------
// Kernel 2a: scores via MFMA + fused masked softmax -> pbuf fp32
// ---------------------------------------------------------------
__global__ __launch_bounds__(256) void scores_mfma(
    const u16* __restrict__ qbuf, const u16* __restrict__ kbuf,
    float* __restrict__ pbuf)
{
  __shared__ float lmax[4][16];
  __shared__ float lsum[4][16];
  const int bid = blockIdx.x;
  const int b = bid & 15, rt = bid >> 4;
  const int t = threadIdx.x;
  const int lane = t & 63, wq = t >> 6;
  const int g = lane >> 4, ln = lane & 15;
  const int i0 = rt * 16;
  const int jbase = (rt < 8) ? 128 : 0;

  const u16* qp  = qbuf + (size_t)(b * 256 + i0 + ln) * 7808 + g * 8;
  const u16* kp0 = kbuf + (size_t)(b * 256 + jbase + wq * 32 + ln) * 7808 + g * 8;
  const u16* kp1 = kp0 + (size_t)16 * 7808;

  f32x4 acc0 = (f32x4)0.f, acc1 = (f32x4)0.f;
  #pragma unroll 4
  for (int c = 0; c < 244; ++c) {
    short8 af = *reinterpret_cast<const short8*>(qp + c * 32);
    short8 b0 = *reinterpret_cast<const short8*>(kp0 + c * 32);
    short8 b1 = *reinterpret_cast<const short8*>(kp1 + c * 32);
    acc0 = __builtin_amdgcn_mfma_f32_16x16x32_bf16(af, b0, acc0, 0, 0, 0);
    acc1 = __builtin_amdgcn_mfma_f32_16x16x32_bf16(af, b1, acc1, 0, 0, 0);
  }

  const float scale = 0.011316967f;    // 1/sqrt(7808)
  float s0[4], s1[4];
  #pragma unroll
  for (int r = 0; r < 4; ++r) { s0[r] = acc0[r] * scale; s1[r] = acc1[r] * scale; }

  float pm[4], ps[4];
  #pragma unroll
  for (int r = 0; r < 4; ++r) {
    float m = fmaxf(s0[r], s1[r]);
    #pragma unroll
    for (int off = 8; off >= 1; off >>= 1) m = fmaxf(m, __shfl_xor(m, off));
    float e = __expf(s0[r] - m) + __expf(s1[r] - m);
    #pragma unroll
    for (int off = 8; off >= 1; off >>= 1) e += __shfl_xor(e, off);
    pm[r] = m; ps[r] = e;
  }
  if (ln == 0) {
    #pragma unroll
    for (int r = 0; r < 4; ++r) {
      lmax[wq][g * 4 + r] = pm[r];
      lsum[wq][g * 4 + r] = ps[r];
    }
  }
  __syncthreads();

  #pragma unroll
  for (int r = 0; r < 4; ++r) {
    int row = g * 4 + r;
    float m0 = lmax[0][row], m1 = lmax[1][row], m2 = lmax[2][row], m3 = lmax[3][row];
    float mm = fmaxf(fmaxf(m0, m1), fmaxf(m2, m3));
    float ss = lsum[0][row] * __expf(m0 - mm) + lsum[1][row] * __expf(m1 - mm)
             + lsum[2][row] * __expf(m2 - mm) + lsum[3][row] * __expf(m3 - mm);
    float inv = 1.0f / ss;
    float p0 = __expf(s0[r] - mm) * inv;
    float p1 = __expf(s1[r] - mm) * inv;
    float* prow = pbuf + (size_t)(b * 256 + i0 + row) * 128 + wq * 32 + ln;
    prow[0]  = p0;
    prow[16] = p1;
  }
}

// ---------------------------------------------------------------
// Kernel 2b: z = x + P*V via MFMA, bf16 out (raw NCHW layout)
// ---------------------------------------------------------------
__global__ __launch_bounds__(256) void pv_mfma(
    const float* __restrict__ pbuf, const float* __restrict__ x,
    u16* __restrict__ zbuf)
{
  __shared__ u16 pl[128 * 136];   // 34816 B
  __shared__ u16 vt[256 * 40];    // 20480 B
  const int bid = blockIdx.x;
  const int b  = bid >> 6;
  const int hb = (bid >> 5) & 1;
  const int ec = bid & 31;
  const int t = threadIdx.x;
  const int lane = t & 63, wv = t >> 6;
  const int ln = lane & 15, g = lane >> 4;

  const int i0 = hb ? 0 : 128;        // output rows
  const int jbase = hb ? 128 : 0;     // V rows (opposite half)
  const int e0 = ec * 256;
  const float* xb = x + (size_t)b * 2097152;
  const float* pb = pbuf + (size_t)(b * 256 + i0) * 128;

  uint32* plw = reinterpret_cast<uint32*>(pl);
  #pragma unroll
  for (int it = 0; it < 32; ++it) {
    int idx = t + it * 256;           // 0..8191 u32 units
    int ii = idx >> 6, jjp = idx & 63;
    float2 f2 = *reinterpret_cast<const float2*>(pb + ii * 128 + jjp * 2);
    plw[ii * 68 + jjp] = pack2(f2.x, f2.y);
  }

  f32x4 acc[2][16];
  #pragma unroll
  for (int mt = 0; mt < 2; ++mt)
    #pragma unroll
    for (int nt = 0; nt < 16; ++nt) acc[mt][nt] = (f32x4)0.f;

  uint32* vtw = reinterpret_cast<uint32*>(vt);
  for (int ks = 0; ks < 4; ++ks) {
    __syncthreads();
    #pragma unroll
    for (int it = 0; it < 16; ++it) {
      int idx = t + it * 256;         // 0..4095
      int e = idx & 255, jp = idx >> 8;   // jp 0..15 (j-pair)
      const float* vr = xb + (size_t)(jbase + ks * 32 + jp * 2) * 8192 + e0 + e;
      float f0 = vr[0];
      float f1 = vr[8192];
      vtw[e * 20 + jp] = pack2(f0, f1);
    }
    __syncthreads();
    short8 af[2];
    #pragma unroll
    for (int mt = 0; mt < 2; ++mt) {
      int row = wv * 32 + mt * 16 + ln;
      af[mt] = *reinterpret_cast<const short8*>(&pl[row * 136 + ks * 32 + g * 8]);
    }
    #pragma unroll
    for (int nt = 0; nt < 16; ++nt) {
      int e = nt * 16 + ln;
      short8 bf = *reinterpret_cast<const short8*>(&vt[e * 40 + g * 8]);
      acc[0][nt] = __builtin_amdgcn_mfma_f32_16x16x32_bf16(af[0], bf, acc[0][nt], 0, 0, 0);
      acc[1][nt] = __builtin_amdgcn_mfma_f32_16x16x32_bf16(af[1], bf, acc[1][nt], 0, 0, 0);
    }
  }

  #pragma unroll
  for (int mt = 0; mt < 2; ++mt) {
    #pragma unroll
    for (int r = 0; r < 4; ++r) {
      int i = i0 + wv * 32 + mt * 16 + g * 4 + r;
      const float* xr = xb + (size_t)i * 8192 + e0 + ln;
      u16* zr = zbuf + (size_t)(b * 256 + i) * 8192 + e0 + ln;
      #pragma unroll
      for (int nt = 0; nt < 16; ++nt) {
        float z = xr[nt * 16] + acc[mt][nt][r];
        zr[nt * 16] = f2bf(z);
      }
    }
  }
}

// ---------------------------------------------------------------
// Kernel 3: y = LeakyReLU(conv(z, wV) + bV) via MFMA, fp32 out
// Same barrier-free structure as conv_kq: weights direct from global.
// ---------------------------------------------------------------
__global__ __launch_bounds__(256) void conv_out_mfma(
    const u16* __restrict__ zbuf, const u16* __restrict__ wpV,
    const float* __restrict__ bV, float* __restrict__ out)
{
  __shared__ u16 xt[136 * 64];
  const int bid = blockIdx.x;
  const int b = bid >> 8, w = bid & 255;
  const int t = threadIdx.x;
  const int lane = t & 63, wv = t >> 6;
  const int ln = lane & 15, g = lane >> 4;

  {
    const u16* zb = zbuf + (size_t)b * 2097152 + (size_t)w * 128;
    #pragma unroll
    for (int it = 0; it < 8; ++it) {
      int idx = t + it * 256;
      int h = idx & 127, gq = idx >> 7;
      int ci0 = gq * 4;
      u16 v0 = zb[(size_t)(ci0 + 0) * 32768 + h];
      u16 v1 = zb[(size_t)(ci0 + 1) * 32768 + h];
      u16 v2 = zb[(size_t)(ci0 + 2) * 32768 + h];
      u16 v3 = zb[(size_t)(ci0 + 3) * 32768 + h];
      uint2 pk;
      pk.x = (uint32)v0 | ((uint32)v1 << 16);
      pk.y = (uint32)v2 | ((uint32)v3 << 16);
      int col = ci0 ^ ((h & 7) << 3);
      *reinterpret_cast<uint2*>(&xt[h * 64 + col]) = pk;
    }
    if (t < 128) {
      int h = 128 + (t >> 4), gq = t & 15;
      *reinterpret_cast<uint2*>(&xt[h * 64 + gq * 4]) = make_uint2(0u, 0u);
    }
  }
  __syncthreads();

  f32x4 acc[8];
  #pragma unroll
  for (int j = 0; j < 8; ++j) acc[j] = (f32x4)0.f;

  for (int kw = 0; kw < 7; ++kw) {
    #pragma unroll
    for (int ks = 0; ks < 2; ++ks) {
      const int kb = ks * 32 + g * 8;
      const size_t woff = (size_t)(kw * 64 + wv * 16 + ln) * 64 + kb;
      short8 aV = *reinterpret_cast<const short8*>(wpV + woff);
      #pragma unroll
      for (int j = 0; j < 8; ++j) {
        int row = j * 16 + ln + kw;
        int col = kb ^ ((row & 7) << 3);
        short8 bf = *reinterpret_cast<const short8*>(&xt[row * 64 + col]);
        acc[j] = __builtin_amdgcn_mfma_f32_16x16x32_bf16(aV, bf, acc[j], 0, 0, 0);
      }
    }
  }

  #pragma unroll
  for (int r = 0; r < 4; ++r) {
    int co = wv * 16 + g * 4 + r;
    float bv = bV[co];
    size_t base = ((size_t)(b * 64 + co) * 256 + w) * 122;
    #pragma unroll
    for (int j = 0; j < 8; ++j) {
      int n = j * 16 + ln;
      if (n < 122) {
        float y = acc[j][r] + bv;
        out[base + n] = (y >= 0.f) ? y : 0.2f * y;
      }
    }
  }
}

// ---------------------------------------------------------------
extern "C" void kernel_launch(void* const* d_in, const int* in_sizes, int n_in,
                              void* d_out, int out_size, void* d_ws, size_t ws_size,
                              hipStream_t stream) {
  const float* x  = (const float*)d_in[0];
  const float* wK = (const float*)d_in[1];
  const float* bK = (const float*)d_in[2];
  const float* wQ = (const float*)d_in[3];
  const float* bQ = (const float*)d_in[4];
  const float* wV = (const float*)d_in[5];
  const float* bV = (const float*)d_in[6];
  float* out = (float*)d_out;

  // workspace layout (133.4 MB total):
  // [0)            zbuf bf16 67108864 B  (qbuf aliases it; qbuf dead after scores)
  // [67108864)     kbuf bf16 63963136 B
  // [131072000)    pbuf fp32  2097152 B
  // [133169152)    wpK/wpQ/wpV bf16 57344 B each
  char* ws = (char*)d_ws;
  u16* qbuf  = (u16*)ws;
  u16* zbuf  = (u16*)ws;
  u16* kbuf  = (u16*)(ws + 67108864);
  float* pbuf = (float*)(ws + 131072000);
  u16* wpK = (u16*)(ws + 133169152);
  u16* wpQ = (u16*)(ws + 133226496);
  u16* wpV = (u16*)(ws + 133283840);

  prep_weights<<<dim3(336), dim3(256), 0, stream>>>(wK, wQ, wV, wpK, wpQ, wpV);
  conv_kq_mfma<<<dim3(16 * 256), dim3(256), 0, stream>>>(x, wpK, wpQ, bK, bQ, qbuf, kbuf);
  scores_mfma<<<dim3(256), dim3(256), 0, stream>>>(qbuf, kbuf, pbuf);
  pv_mfma<<<dim3(1024), dim3(256), 0, stream>>>(pbuf, x, zbuf);
  conv_out_mfma<<<dim3(16 * 256), dim3(256), 0, stream>>>(zbuf, wpV, bV, out);
}